// Round 7
// baseline (552.452 us; speedup 1.0000x reference)
//
#include <hip/hip_runtime.h>
#include <math.h>

#define N_NODES 262144
#define N_EDGES 524288
#define NB      16
#define N_PER   16384
#define KKEEP   8192
#define DIM     128
#define NEG_SLOPE 0.01f
#define CHUNK   2048        // sort chunk size (8 chunks per graph)

// ---- output layout (floats) ----
#define X_OUT   0                     // 131072*128 = 16777216
#define X_EI    16777216              // 2*E = 1048576
#define X_EW    17825792              // E   = 524288
#define X_BATCH 18350080              // B*K = 131072

typedef short s8v __attribute__((ext_vector_type(8)));   // 8 bf16 in 4 VGPRs
typedef float f4v __attribute__((ext_vector_type(4)));   // MFMA accumulator

__device__ __forceinline__ unsigned long long pack_key(float sc, int localIdx) {
    unsigned int u = __float_as_uint(sc);
    u = (u & 0x80000000u) ? ~u : (u | 0x80000000u);   // order-preserving map
    unsigned int inv = ~u;                            // descending score
    return ((unsigned long long)inv << 32) | (unsigned int)localIdx;
}

// RN float->bf16 (round-nearest-even), returns low 16 bits
__device__ __forceinline__ unsigned int f2bf(float x) {
    unsigned int u = __float_as_uint(x);
    return (u + 0x7FFFu + ((u >> 16) & 1u)) >> 16;
}
__device__ __forceinline__ float bf2f(unsigned int h) { return __uint_as_float(h << 16); }

// ================= K1: init =================
__global__ void k_init(float* deg, int* count, int* mapping, const float* pw, float* normPw) {
    int n = blockIdx.x * 256 + threadIdx.x;
    if (n < N_NODES) { deg[n] = 1.0f; count[n] = 0; mapping[n] = -1; }
    if (n == 0) {
        float s = 0.f;
        for (int i = 0; i < DIM; i++) s += pw[i] * pw[i];
        normPw[0] = sqrtf(s);
    }
}

// ===== K_wprep: one-time W[k][n] -> 3-way bf16 Dekker split, transposed [n][k] =====
__global__ void k_wprep(const float* Wg, unsigned short* Wt0, unsigned short* Wt1,
                        unsigned short* Wt2) {
    int idx = blockIdx.x * 256 + threadIdx.x;     // 16384 elems over 64 blocks
    if (idx >= DIM * DIM) return;
    int k = idx >> 7, n = idx & 127;
    float wv = Wg[k * 128 + n];
    unsigned int h = f2bf(wv);
    float r1 = wv - bf2f(h);          // exact
    unsigned int m = f2bf(r1);
    float r2 = r1 - bf2f(m);          // exact
    unsigned int lo = f2bf(r2);
    Wt0[n * 128 + k] = (unsigned short)h;
    Wt1[n * 128 + k] = (unsigned short)m;
    Wt2[n * 128 + k] = (unsigned short)lo;
}

// ================= K2: degree + in-edge counts =================
__global__ void k_deg(const int* col, const float* w, float* deg, int* count) {
    int e = blockIdx.x * 256 + threadIdx.x;
    if (e >= N_EDGES) return;
    int c = col[e];
    atomicAdd(&deg[c], w[e]);
    atomicAdd(&count[c], 1);
}

// ================= K3a: per-block exclusive scan (2048/block) =================
__global__ void k_scan1(const int* count, int* offs, int* blockSums) {
    __shared__ int s[2048];
    int base = blockIdx.x * 2048;
    int t = threadIdx.x;  // 1024 threads
    s[t]        = count[base + t];
    s[t + 1024] = count[base + t + 1024];
    __syncthreads();
    for (int off = 1; off < 2048; off <<= 1) {
        int a0 = (t >= off)        ? s[t - off]        : 0;
        int a1 = (t + 1024 >= off) ? s[t + 1024 - off] : 0;
        __syncthreads();
        s[t]        += a0;
        s[t + 1024] += a1;
        __syncthreads();
    }
    offs[base + t]        = s[t]        - count[base + t];
    offs[base + t + 1024] = s[t + 1024] - count[base + t + 1024];
    if (t == 0) blockSums[blockIdx.x] = s[2047];
}

// ================= K3b: scan the 128 block sums =================
__global__ void k_scan2(int* blockSums, int* offs) {
    if (threadIdx.x == 0) {
        int run = 0;
        for (int b = 0; b < 128; b++) { int v = blockSums[b]; blockSums[b] = run; run += v; }
        offs[N_NODES] = run;   // == E
    }
}

// ================= K3c: add block offsets, zero cursor, deg->dinv =================
__global__ void k_fixup(int* offs, int* count, float* deg, const int* blockSums) {
    int n = blockIdx.x * 256 + threadIdx.x;
    if (n >= N_NODES) return;
    offs[n] += blockSums[n >> 11];
    count[n] = 0;
    float d = deg[n];
    deg[n] = (d > 0.f) ? (1.0f / sqrtf(d)) : 0.f;   // in-place -> dinv
}

// ================= K4: scatter edges into CSR-by-dst =================
__global__ void k_scatter(const int* row, const int* col, const float* w, const float* dinv,
                          const int* offs, int* cursor, int* ssrc, float* scoef) {
    int e = blockIdx.x * 256 + threadIdx.x;
    if (e >= N_EDGES) return;
    int r = row[e], c = col[e];
    int pos = atomicAdd(&cursor[c], 1);
    int slot = offs[c] + pos;
    ssrc[slot]  = r;
    scoef[slot] = (dinv[r] * w[e]) * dinv[c];
}

// ======== K5: gather-aggregate (A_norm @ x), 32 lanes/node, MLP-batched ========
// R4->R5: batching edges 4/2 + self-row hoist cut 117.8 -> <89 us.
// Accumulation ORDER unchanged (j, j+1, ... then self) -> bitwise-identical result.
__global__ void k_aggregate(const float* x, const float* dinv, const int* offs,
                            const int* ssrc, const float* scoef, float* agg) {
    int g = blockIdx.x * 256 + threadIdx.x;
    int node = g >> 5, d = g & 31;
    const float4* x4 = (const float4*)x;
    int s = offs[node], e = offs[node + 1];

    float4 vs = x4[(size_t)node * 32 + d];    // self row: in flight during edge loop
    float di = dinv[node];

    float4 acc = make_float4(0.f, 0.f, 0.f, 0.f);
    int j = s;
    while (j + 4 <= e) {
        int   s0 = ssrc[j],  s1 = ssrc[j + 1],  s2 = ssrc[j + 2],  s3 = ssrc[j + 3];
        float c0 = scoef[j], c1 = scoef[j + 1], c2 = scoef[j + 2], c3 = scoef[j + 3];
        float4 va = x4[(size_t)s0 * 32 + d];
        float4 vb = x4[(size_t)s1 * 32 + d];
        float4 vc = x4[(size_t)s2 * 32 + d];
        float4 vd = x4[(size_t)s3 * 32 + d];
        acc.x += c0 * va.x; acc.y += c0 * va.y; acc.z += c0 * va.z; acc.w += c0 * va.w;
        acc.x += c1 * vb.x; acc.y += c1 * vb.y; acc.z += c1 * vb.z; acc.w += c1 * vb.w;
        acc.x += c2 * vc.x; acc.y += c2 * vc.y; acc.z += c2 * vc.z; acc.w += c2 * vc.w;
        acc.x += c3 * vd.x; acc.y += c3 * vd.y; acc.z += c3 * vd.z; acc.w += c3 * vd.w;
        j += 4;
    }
    if (j + 2 <= e) {
        int   s0 = ssrc[j],  s1 = ssrc[j + 1];
        float c0 = scoef[j], c1 = scoef[j + 1];
        float4 va = x4[(size_t)s0 * 32 + d];
        float4 vb = x4[(size_t)s1 * 32 + d];
        acc.x += c0 * va.x; acc.y += c0 * va.y; acc.z += c0 * va.z; acc.w += c0 * va.w;
        acc.x += c1 * vb.x; acc.y += c1 * vb.y; acc.z += c1 * vb.z; acc.w += c1 * vb.w;
        j += 2;
    }
    if (j < e) {
        int   s0 = ssrc[j];
        float c0 = scoef[j];
        float4 va = x4[(size_t)s0 * 32 + d];
        acc.x += c0 * va.x; acc.y += c0 * va.y; acc.z += c0 * va.z; acc.w += c0 * va.w;
    }
    float cf = di * di;                 // self-loop: dinv*1*dinv (added last, as before)
    acc.x += cf * vs.x; acc.y += cf * vs.y; acc.z += cf * vs.z; acc.w += cf * vs.w;
    ((float4*)agg)[(size_t)node * 32 + d] = acc;
}

// ======== K6: LDS MFMA GEMM (R5 structure) + software-pipelined reg staging ========
// R6 post-mortem: LDS-free gemm = uncoalesced per-lane fragment gathers -> 160us
// latency-bound (all pipes <18%). Reverted to R5's LDS kernel (90us verified) and
// fixed R5's real limiter: 3-phase serialization. Pipeline per chunk:
//   ds_write(kh) | barrier | issue global loads(kh+1) ; ds_read frags + 128 MFMA
//   (loads in flight under MFMA) ; split(kh+1) in regs | barrier
// All loads consumed before each barrier -> the compiler's vmcnt(0) barrier drain
// costs nothing. Staging pattern / swizzle / MFMA term order / epilogue verbatim
// R5 -> bitwise-identical result (absmax must stay 2.235931).
__global__ __launch_bounds__(256, 2) void k_gemm(float* hio,
                                                 const unsigned short* Wt0,
                                                 const unsigned short* Wt1,
                                                 const unsigned short* Wt2,
                                                 const float* bias, const float* pw,
                                                 const float* normPw, float* score) {
    __shared__ __align__(16) char smem[49152];
    char* sA0 = smem;                  // [128][32] bf16 = 8KB per split level
    char* sA1 = smem + 8192;
    char* sA2 = smem + 16384;
    char* sW0 = smem + 24576;
    char* sW1 = smem + 32768;
    char* sW2 = smem + 40960;

    int tid = threadIdx.x;
    int l   = tid & 63;
    int w   = tid >> 6;          // wave id 0..3 -> rows w*32..w*32+31
    int l15 = l & 15, l4 = l >> 4;
    int row0 = blockIdx.x * 128;

    f4v acc[2][8];
#pragma unroll
    for (int mt = 0; mt < 2; mt++)
#pragma unroll
        for (int nt = 0; nt < 8; nt++)
#pragma unroll
            for (int r = 0; r < 4; r++) acc[mt][nt][r] = 0.f;

    // staged (registers): per i=0,1 -> A split 3x uint4, W 3x uint4
    uint4 aPk[2][3];
    uint4 wPk[2][3];

    // ---- prologue: load + split chunk 0 into regs ----
#pragma unroll
    for (int i = 0; i < 2; i++) {
        int f = tid + i * 256;
        int r = f >> 2, c = f & 3;
        const float* src = hio + (size_t)(row0 + r) * 128 + 0 * 32 + c * 8;
        float4 v0 = *(const float4*)(src);
        float4 v1 = *(const float4*)(src + 4);
        float a[8] = {v0.x, v0.y, v0.z, v0.w, v1.x, v1.y, v1.z, v1.w};
        unsigned int h[8], m[8], lo[8];
#pragma unroll
        for (int j = 0; j < 8; j++) {
            h[j] = f2bf(a[j]);
            float r1 = a[j] - bf2f(h[j]);
            m[j] = f2bf(r1);
            float r2 = r1 - bf2f(m[j]);
            lo[j] = f2bf(r2);
        }
        aPk[i][0] = make_uint4(h[0] | (h[1] << 16), h[2] | (h[3] << 16),
                               h[4] | (h[5] << 16), h[6] | (h[7] << 16));
        aPk[i][1] = make_uint4(m[0] | (m[1] << 16), m[2] | (m[3] << 16),
                               m[4] | (m[5] << 16), m[6] | (m[7] << 16));
        aPk[i][2] = make_uint4(lo[0] | (lo[1] << 16), lo[2] | (lo[3] << 16),
                               lo[4] | (lo[5] << 16), lo[6] | (lo[7] << 16));
        size_t gb = (size_t)r * 256 + 0 * 64 + c * 16;   // W bytes: [n][128k] bf16
        wPk[i][0] = *(const uint4*)((const char*)Wt0 + gb);
        wPk[i][1] = *(const uint4*)((const char*)Wt1 + gb);
        wPk[i][2] = *(const uint4*)((const char*)Wt2 + gb);
    }

#pragma unroll
    for (int kh = 0; kh < 4; kh++) {
        // ---- write phase: staged regs -> LDS (swizzled, verbatim R5 layout) ----
#pragma unroll
        for (int i = 0; i < 2; i++) {
            int f = tid + i * 256;
            int r = f >> 2, c = f & 3;
            int off = r * 64 + ((c ^ ((r >> 1) & 3)) * 16);
            *(uint4*)(sA0 + off) = aPk[i][0];
            *(uint4*)(sA1 + off) = aPk[i][1];
            *(uint4*)(sA2 + off) = aPk[i][2];
            *(uint4*)(sW0 + off) = wPk[i][0];
            *(uint4*)(sW1 + off) = wPk[i][1];
            *(uint4*)(sW2 + off) = wPk[i][2];
        }
        __syncthreads();

        // ---- issue next-chunk global loads (in flight under the MFMA burst) ----
        float4 aR[2][2];
        uint4  wR[2][3];
        if (kh < 3) {
#pragma unroll
            for (int i = 0; i < 2; i++) {
                int f = tid + i * 256;
                int r = f >> 2, c = f & 3;
                const float* src = hio + (size_t)(row0 + r) * 128 + (kh + 1) * 32 + c * 8;
                aR[i][0] = *(const float4*)(src);
                aR[i][1] = *(const float4*)(src + 4);
                size_t gb = (size_t)r * 256 + (kh + 1) * 64 + c * 16;
                wR[i][0] = *(const uint4*)((const char*)Wt0 + gb);
                wR[i][1] = *(const uint4*)((const char*)Wt1 + gb);
                wR[i][2] = *(const uint4*)((const char*)Wt2 + gb);
            }
        }

        // ---- compute phase: fragments + MFMA (verbatim R5 order) ----
        s8v ah[2], am[2], al[2];
#pragma unroll
        for (int mt = 0; mt < 2; mt++) {
            int r = w * 32 + mt * 16 + l15;
            int off = r * 64 + ((l4 ^ ((r >> 1) & 3)) * 16);
            ah[mt] = *(const s8v*)(sA0 + off);
            am[mt] = *(const s8v*)(sA1 + off);
            al[mt] = *(const s8v*)(sA2 + off);
        }
#pragma unroll
        for (int nt = 0; nt < 8; nt++) {
            int rn = nt * 16 + l15;
            int offb = rn * 64 + ((l4 ^ ((rn >> 1) & 3)) * 16);
            s8v b0 = *(const s8v*)(sW0 + offb);
            s8v b1 = *(const s8v*)(sW1 + offb);
            s8v b2 = *(const s8v*)(sW2 + offb);
#pragma unroll
            for (int mt = 0; mt < 2; mt++) {
                acc[mt][nt] = __builtin_amdgcn_mfma_f32_16x16x32_bf16(ah[mt], b0, acc[mt][nt], 0, 0, 0);
                acc[mt][nt] = __builtin_amdgcn_mfma_f32_16x16x32_bf16(ah[mt], b1, acc[mt][nt], 0, 0, 0);
                acc[mt][nt] = __builtin_amdgcn_mfma_f32_16x16x32_bf16(am[mt], b0, acc[mt][nt], 0, 0, 0);
                acc[mt][nt] = __builtin_amdgcn_mfma_f32_16x16x32_bf16(am[mt], b1, acc[mt][nt], 0, 0, 0);
                acc[mt][nt] = __builtin_amdgcn_mfma_f32_16x16x32_bf16(ah[mt], b2, acc[mt][nt], 0, 0, 0);
                acc[mt][nt] = __builtin_amdgcn_mfma_f32_16x16x32_bf16(al[mt], b0, acc[mt][nt], 0, 0, 0);
                acc[mt][nt] = __builtin_amdgcn_mfma_f32_16x16x32_bf16(am[mt], b2, acc[mt][nt], 0, 0, 0);
                acc[mt][nt] = __builtin_amdgcn_mfma_f32_16x16x32_bf16(al[mt], b1, acc[mt][nt], 0, 0, 0);
            }
        }

        // ---- split next chunk in regs (consumes the in-flight loads) ----
        if (kh < 3) {
#pragma unroll
            for (int i = 0; i < 2; i++) {
                float a[8] = {aR[i][0].x, aR[i][0].y, aR[i][0].z, aR[i][0].w,
                              aR[i][1].x, aR[i][1].y, aR[i][1].z, aR[i][1].w};
                unsigned int h[8], m[8], lo[8];
#pragma unroll
                for (int j = 0; j < 8; j++) {
                    h[j] = f2bf(a[j]);
                    float r1 = a[j] - bf2f(h[j]);
                    m[j] = f2bf(r1);
                    float r2 = r1 - bf2f(m[j]);
                    lo[j] = f2bf(r2);
                }
                aPk[i][0] = make_uint4(h[0] | (h[1] << 16), h[2] | (h[3] << 16),
                                       h[4] | (h[5] << 16), h[6] | (h[7] << 16));
                aPk[i][1] = make_uint4(m[0] | (m[1] << 16), m[2] | (m[3] << 16),
                                       m[4] | (m[5] << 16), m[6] | (m[7] << 16));
                aPk[i][2] = make_uint4(lo[0] | (lo[1] << 16), lo[2] | (lo[3] << 16),
                                       lo[4] | (lo[5] << 16), lo[6] | (lo[7] << 16));
                wPk[i][0] = wR[i][0];
                wPk[i][1] = wR[i][1];
                wPk[i][2] = wR[i][2];
            }
        }
        __syncthreads();
    }

    // ---- epilogue: bias + leaky + h write (in-place) + score (verbatim R5) ----
    float bv[8], pv[8];
#pragma unroll
    for (int nt = 0; nt < 8; nt++) {
        bv[nt] = bias[nt * 16 + l15];
        pv[nt] = pw[nt * 16 + l15];
    }
    float nrm = normPw[0];
    float sp[2][4];
#pragma unroll
    for (int mt = 0; mt < 2; mt++)
#pragma unroll
        for (int r = 0; r < 4; r++) sp[mt][r] = 0.f;

#pragma unroll
    for (int mt = 0; mt < 2; mt++) {
#pragma unroll
        for (int r = 0; r < 4; r++) {
            int row = row0 + w * 32 + mt * 16 + l4 * 4 + r;
#pragma unroll
            for (int nt = 0; nt < 8; nt++) {
                float v = acc[mt][nt][r] + bv[nt];
                v = (v >= 0.f) ? v : NEG_SLOPE * v;
                hio[(size_t)row * 128 + nt * 16 + l15] = v;
                sp[mt][r] += v * pv[nt];
            }
        }
    }
#pragma unroll
    for (int m = 1; m < 16; m <<= 1) {
#pragma unroll
        for (int mt = 0; mt < 2; mt++)
#pragma unroll
            for (int r = 0; r < 4; r++) sp[mt][r] += __shfl_xor(sp[mt][r], m, 64);
    }
    if (l15 == 0) {
#pragma unroll
        for (int mt = 0; mt < 2; mt++)
#pragma unroll
            for (int r = 0; r < 4; r++) {
                int row = row0 + w * 32 + mt * 16 + l4 * 4 + r;
                score[row] = tanhf(sp[mt][r] / nrm);
            }
    }
}

// ================= K7: per-chunk LDS bitonic sort (128 blocks x 2048 keys) =================
__global__ void __launch_bounds__(1024) k_sortchunks(const float* score,
                                                     unsigned long long* keys) {
    __shared__ unsigned long long a[CHUNK];     // 16 KB
    int base = blockIdx.x * CHUNK;              // chunk-aligned within a graph
    int t = threadIdx.x;
#pragma unroll
    for (int i = 0; i < CHUNK / 1024; i++) {
        int p = t + i * 1024;
        int node = base + p;
        a[p] = pack_key(score[node], node & (N_PER - 1));
    }
    __syncthreads();
    for (int k = 2; k <= CHUNK; k <<= 1) {
        for (int j = k >> 1; j > 0; j >>= 1) {
#pragma unroll
            for (int q = 0; q < CHUNK / 2048; q++) {
                int tt = t + q * 1024;
                int i = ((tt & ~(j - 1)) << 1) | (tt & (j - 1));
                int l = i | j;
                bool asc = ((i & k) == 0);
                unsigned long long x = a[i], y = a[l];
                if ((x > y) == asc) { a[i] = y; a[l] = x; }
            }
            __syncthreads();
        }
    }
#pragma unroll
    for (int i = 0; i < CHUNK / 1024; i++) {
        int p = t + i * 1024;
        keys[base + p] = a[p];
    }
}

// ================= K8: rank via binary search over sorted chunks, fused extract =================
__global__ void k_rank(const float* score, const unsigned long long* keys,
                       int* perm, int* mapping, float* out) {
    int n = blockIdx.x * 256 + threadIdx.x;
    if (n >= N_NODES) return;
    int g = n >> 14;
    unsigned long long key = pack_key(score[n], n & (N_PER - 1));
    const unsigned long long* gb = keys + ((size_t)g << 14);
    int r = 0;
#pragma unroll
    for (int c = 0; c < N_PER / CHUNK; c++) {
        const unsigned long long* ch = gb + c * CHUNK;
        int lo = 0, hi = CHUNK;
        while (lo < hi) {
            int mid = (lo + hi) >> 1;
            if (ch[mid] < key) lo = mid + 1; else hi = mid;
        }
        r += lo;
    }
    if (r < KKEEP) {
        int i = (g << 13) + r;
        perm[i] = n;
        mapping[n] = i;
        out[X_BATCH + i] = (float)g;
    }
}

// ================= K10: gate kept rows =================
__global__ void k_gate(const float* h, const float* score, const int* perm, float* out) {
    int g = blockIdx.x * 256 + threadIdx.x;
    int i = g >> 5, d = g & 31;
    int node = perm[i];
    float sc = score[node];
    float4 v = ((const float4*)h)[(size_t)node * 32 + d];
    v.x *= sc; v.y *= sc; v.z *= sc; v.w *= sc;
    ((float4*)(out + X_OUT))[(size_t)i * 32 + d] = v;
}

// ================= K11: relabel edges =================
__global__ void k_edges(const int* row, const int* col, const float* w,
                        const int* mapping, float* out) {
    int e = blockIdx.x * 256 + threadIdx.x;
    if (e >= N_EDGES) return;
    int mr = mapping[row[e]], mc = mapping[col[e]];
    bool valid = (mr >= 0) && (mc >= 0);
    out[X_EI + e]           = valid ? (float)mr : 0.f;
    out[X_EI + N_EDGES + e] = valid ? (float)mc : 0.f;
    out[X_EW + e]           = valid ? w[e] : 0.f;
}

extern "C" void kernel_launch(void* const* d_in, const int* in_sizes, int n_in,
                              void* d_out, int out_size, void* d_ws, size_t ws_size,
                              hipStream_t stream) {
    const float* x     = (const float*)d_in[0];
    const int*   ei    = (const int*)d_in[1];
    const float* ew    = (const float*)d_in[2];
    const float* Wc    = (const float*)d_in[4];
    const float* bias  = (const float*)d_in[5];
    const float* pw    = (const float*)d_in[6];
    float* out = (float*)d_out;

    const int* rowp = ei;
    const int* colp = ei + N_EDGES;

    char* wsb = (char*)d_ws;
    float* agg     = (float*)(wsb);                          // N*128*4 = 134217728
    float* dinv    = (float*)(wsb + 134217728);              // N*4 (deg, then dinv)
    int*   count   = (int*)  (wsb + 135266304);              // N*4 (counts, then cursor)
    int*   offs    = (int*)  (wsb + 136314880);              // (N+1)*4 padded
    int*   ssrc    = (int*)  (wsb + 137363712);              // E*4
    float* scoef   = (float*)(wsb + 139460864);              // E*4
    float* score   = (float*)(wsb + 141557760);              // N*4
    unsigned long long* keys = (unsigned long long*)(wsb + 142606336);  // N*8
    int*   perm    = (int*)  (wsb + 144703488);              // B*K*4
    int*   mapping = (int*)  (wsb + 145227776);              // N*4
    int*   blockSums = (int*)(wsb + 146276352);              // 128*4 padded
    float* normPw  = (float*)(wsb + 146277376);              // 4
    unsigned short* Wt0 = (unsigned short*)(wsb + 146278400);  // 128*128*2 = 32768
    unsigned short* Wt1 = (unsigned short*)(wsb + 146311168);  // 32768
    unsigned short* Wt2 = (unsigned short*)(wsb + 146343936);  // 32768

    k_init   <<<N_NODES / 256, 256, 0, stream>>>(dinv, count, mapping, pw, normPw);
    k_wprep  <<<64, 256, 0, stream>>>(Wc, Wt0, Wt1, Wt2);
    k_deg    <<<N_EDGES / 256, 256, 0, stream>>>(colp, ew, dinv, count);
    k_scan1  <<<128, 1024, 0, stream>>>(count, offs, blockSums);
    k_scan2  <<<1, 64, 0, stream>>>(blockSums, offs);
    k_fixup  <<<N_NODES / 256, 256, 0, stream>>>(offs, count, dinv, blockSums);
    k_scatter<<<N_EDGES / 256, 256, 0, stream>>>(rowp, colp, ew, dinv, offs, count, ssrc, scoef);
    k_aggregate<<<(N_NODES * 32) / 256, 256, 0, stream>>>(x, dinv, offs, ssrc, scoef, agg);
    k_gemm   <<<N_NODES / 128, 256, 0, stream>>>(agg, Wt0, Wt1, Wt2, bias, pw, normPw, score);
    k_sortchunks<<<N_NODES / CHUNK, 1024, 0, stream>>>(score, keys);
    k_rank   <<<N_NODES / 256, 256, 0, stream>>>(score, keys, perm, mapping, out);
    k_gate   <<<(NB * KKEEP * 32) / 256, 256, 0, stream>>>(agg, score, perm, out);
    k_edges  <<<N_EDGES / 256, 256, 0, stream>>>(rowp, colp, ew, mapping, out);
}

// Round 8
// 548.945 us; speedup vs baseline: 1.0064x; 1.0064x over previous
//
#include <hip/hip_runtime.h>
#include <math.h>

#define N_NODES 262144
#define N_EDGES 524288
#define NB      16
#define N_PER   16384
#define KKEEP   8192
#define DIM     128
#define NEG_SLOPE 0.01f
#define CHUNK   2048        // sort chunk size (8 chunks per graph)

// ---- output layout (floats) ----
#define X_OUT   0                     // 131072*128 = 16777216
#define X_EI    16777216              // 2*E = 1048576
#define X_EW    17825792              // E   = 524288
#define X_BATCH 18350080              // B*K = 131072

typedef short s8v __attribute__((ext_vector_type(8)));   // 8 bf16 in 4 VGPRs
typedef float f4v __attribute__((ext_vector_type(4)));   // MFMA accumulator

__device__ __forceinline__ unsigned long long pack_key(float sc, int localIdx) {
    unsigned int u = __float_as_uint(sc);
    u = (u & 0x80000000u) ? ~u : (u | 0x80000000u);   // order-preserving map
    unsigned int inv = ~u;                            // descending score
    return ((unsigned long long)inv << 32) | (unsigned int)localIdx;
}

// RN float->bf16 (round-nearest-even), returns low 16 bits
__device__ __forceinline__ unsigned int f2bf(float x) {
    unsigned int u = __float_as_uint(x);
    return (u + 0x7FFFu + ((u >> 16) & 1u)) >> 16;
}
__device__ __forceinline__ float bf2f(unsigned int h) { return __uint_as_float(h << 16); }

// ================= K1: init =================
__global__ void k_init(float* deg, int* count, int* mapping, const float* pw, float* normPw) {
    int n = blockIdx.x * 256 + threadIdx.x;
    if (n < N_NODES) { deg[n] = 1.0f; count[n] = 0; mapping[n] = -1; }
    if (n == 0) {
        float s = 0.f;
        for (int i = 0; i < DIM; i++) s += pw[i] * pw[i];
        normPw[0] = sqrtf(s);
    }
}

// ===== K_wprep: one-time W[k][n] -> 3-way bf16 Dekker split, transposed [n][k] =====
__global__ void k_wprep(const float* Wg, unsigned short* Wt0, unsigned short* Wt1,
                        unsigned short* Wt2) {
    int idx = blockIdx.x * 256 + threadIdx.x;     // 16384 elems over 64 blocks
    if (idx >= DIM * DIM) return;
    int k = idx >> 7, n = idx & 127;
    float wv = Wg[k * 128 + n];
    unsigned int h = f2bf(wv);
    float r1 = wv - bf2f(h);          // exact
    unsigned int m = f2bf(r1);
    float r2 = r1 - bf2f(m);          // exact
    unsigned int lo = f2bf(r2);
    Wt0[n * 128 + k] = (unsigned short)h;
    Wt1[n * 128 + k] = (unsigned short)m;
    Wt2[n * 128 + k] = (unsigned short)lo;
}

// ================= K2: degree + in-edge counts =================
__global__ void k_deg(const int* col, const float* w, float* deg, int* count) {
    int e = blockIdx.x * 256 + threadIdx.x;
    if (e >= N_EDGES) return;
    int c = col[e];
    atomicAdd(&deg[c], w[e]);
    atomicAdd(&count[c], 1);
}

// ================= K3a: per-block exclusive scan (2048/block) =================
__global__ void k_scan1(const int* count, int* offs, int* blockSums) {
    __shared__ int s[2048];
    int base = blockIdx.x * 2048;
    int t = threadIdx.x;  // 1024 threads
    s[t]        = count[base + t];
    s[t + 1024] = count[base + t + 1024];
    __syncthreads();
    for (int off = 1; off < 2048; off <<= 1) {
        int a0 = (t >= off)        ? s[t - off]        : 0;
        int a1 = (t + 1024 >= off) ? s[t + 1024 - off] : 0;
        __syncthreads();
        s[t]        += a0;
        s[t + 1024] += a1;
        __syncthreads();
    }
    offs[base + t]        = s[t]        - count[base + t];
    offs[base + t + 1024] = s[t + 1024] - count[base + t + 1024];
    if (t == 0) blockSums[blockIdx.x] = s[2047];
}

// ================= K3b: scan the 128 block sums =================
__global__ void k_scan2(int* blockSums, int* offs) {
    if (threadIdx.x == 0) {
        int run = 0;
        for (int b = 0; b < 128; b++) { int v = blockSums[b]; blockSums[b] = run; run += v; }
        offs[N_NODES] = run;   // == E
    }
}

// ================= K3c: add block offsets, zero cursor, deg->dinv =================
__global__ void k_fixup(int* offs, int* count, float* deg, const int* blockSums) {
    int n = blockIdx.x * 256 + threadIdx.x;
    if (n >= N_NODES) return;
    offs[n] += blockSums[n >> 11];
    count[n] = 0;
    float d = deg[n];
    deg[n] = (d > 0.f) ? (1.0f / sqrtf(d)) : 0.f;   // in-place -> dinv
}

// ================= K4: scatter edges into CSR-by-dst =================
__global__ void k_scatter(const int* row, const int* col, const float* w, const float* dinv,
                          const int* offs, int* cursor, int* ssrc, float* scoef) {
    int e = blockIdx.x * 256 + threadIdx.x;
    if (e >= N_EDGES) return;
    int r = row[e], c = col[e];
    int pos = atomicAdd(&cursor[c], 1);
    int slot = offs[c] + pos;
    ssrc[slot]  = r;
    scoef[slot] = (dinv[r] * w[e]) * dinv[c];
}

// ======== K5: gather-aggregate (A_norm @ x), 32 lanes/node, MLP-batched ========
__global__ void k_aggregate(const float* x, const float* dinv, const int* offs,
                            const int* ssrc, const float* scoef, float* agg) {
    int g = blockIdx.x * 256 + threadIdx.x;
    int node = g >> 5, d = g & 31;
    const float4* x4 = (const float4*)x;
    int s = offs[node], e = offs[node + 1];

    float4 vs = x4[(size_t)node * 32 + d];    // self row: in flight during edge loop
    float di = dinv[node];

    float4 acc = make_float4(0.f, 0.f, 0.f, 0.f);
    int j = s;
    while (j + 4 <= e) {
        int   s0 = ssrc[j],  s1 = ssrc[j + 1],  s2 = ssrc[j + 2],  s3 = ssrc[j + 3];
        float c0 = scoef[j], c1 = scoef[j + 1], c2 = scoef[j + 2], c3 = scoef[j + 3];
        float4 va = x4[(size_t)s0 * 32 + d];
        float4 vb = x4[(size_t)s1 * 32 + d];
        float4 vc = x4[(size_t)s2 * 32 + d];
        float4 vd = x4[(size_t)s3 * 32 + d];
        acc.x += c0 * va.x; acc.y += c0 * va.y; acc.z += c0 * va.z; acc.w += c0 * va.w;
        acc.x += c1 * vb.x; acc.y += c1 * vb.y; acc.z += c1 * vb.z; acc.w += c1 * vb.w;
        acc.x += c2 * vc.x; acc.y += c2 * vc.y; acc.z += c2 * vc.z; acc.w += c2 * vc.w;
        acc.x += c3 * vd.x; acc.y += c3 * vd.y; acc.z += c3 * vd.z; acc.w += c3 * vd.w;
        j += 4;
    }
    if (j + 2 <= e) {
        int   s0 = ssrc[j],  s1 = ssrc[j + 1];
        float c0 = scoef[j], c1 = scoef[j + 1];
        float4 va = x4[(size_t)s0 * 32 + d];
        float4 vb = x4[(size_t)s1 * 32 + d];
        acc.x += c0 * va.x; acc.y += c0 * va.y; acc.z += c0 * va.z; acc.w += c0 * va.w;
        acc.x += c1 * vb.x; acc.y += c1 * vb.y; acc.z += c1 * vb.z; acc.w += c1 * vb.w;
        j += 2;
    }
    if (j < e) {
        int   s0 = ssrc[j];
        float c0 = scoef[j];
        float4 va = x4[(size_t)s0 * 32 + d];
        acc.x += c0 * va.x; acc.y += c0 * va.y; acc.z += c0 * va.z; acc.w += c0 * va.w;
    }
    float cf = di * di;                 // self-loop: dinv*1*dinv (added last, as before)
    acc.x += cf * vs.x; acc.y += cf * vs.y; acc.z += cf * vs.z; acc.w += cf * vs.w;
    ((float4*)agg)[(size_t)node * 32 + d] = acc;
}

// ======== K6: LDS MFMA GEMM (R5 structure) + raw-reg prefetch, unroll-pinned ========
// R7 post-mortem: WRITE_SIZE 132->310MB = scratch spill; the unrolled kh loop let
// the compiler hoist all chunks' prefetch loads -> live-range blowup. Fixes:
//  (1) #pragma unroll 1 on kh loop: exactly ONE iteration's prefetch regs live.
//  (2) prefetch RAW values only (A: 16 VGPR, W: 24 VGPR; W needs no split), Dekker
//      split at next loop-top, outside the MFMA region.
// Overlap mechanism kept: loads issued after the staging barrier, consumed next
// iteration -> latency hides under the 128-MFMA burst; the vmcnt(0) drain at the
// loop-top barrier costs ~0 because loads landed during MFMA.
// Split math / swizzle / MFMA order / epilogue verbatim R5 -> bitwise-identical
// (absmax must stay 2.235931).
__global__ __launch_bounds__(256, 2) void k_gemm(float* hio,
                                                 const unsigned short* Wt0,
                                                 const unsigned short* Wt1,
                                                 const unsigned short* Wt2,
                                                 const float* bias, const float* pw,
                                                 const float* normPw, float* score) {
    __shared__ __align__(16) char smem[49152];
    char* sA0 = smem;                  // [128][32] bf16 = 8KB per split level
    char* sA1 = smem + 8192;
    char* sA2 = smem + 16384;
    char* sW0 = smem + 24576;
    char* sW1 = smem + 32768;
    char* sW2 = smem + 40960;

    int tid = threadIdx.x;
    int l   = tid & 63;
    int w   = tid >> 6;          // wave id 0..3 -> rows w*32..w*32+31
    int l15 = l & 15, l4 = l >> 4;
    int row0 = blockIdx.x * 128;

    // staging coords (constant per thread): i=0,1 -> work item f = tid + i*256
    int sr[2], sc[2], soff[2];
#pragma unroll
    for (int i = 0; i < 2; i++) {
        int f = tid + i * 256;
        sr[i] = f >> 2;
        sc[i] = f & 3;
        soff[i] = sr[i] * 64 + ((sc[i] ^ ((sr[i] >> 1) & 3)) * 16);
    }

    f4v acc[2][8];
#pragma unroll
    for (int mt = 0; mt < 2; mt++)
#pragma unroll
        for (int nt = 0; nt < 8; nt++)
#pragma unroll
            for (int r = 0; r < 4; r++) acc[mt][nt][r] = 0.f;

    // ---- prologue: raw loads of chunk 0 (A fp32 + W pre-split bf16) ----
    float4 aRa[2], aRb[2];
    uint4  wR[2][3];
#pragma unroll
    for (int i = 0; i < 2; i++) {
        const float* src = hio + (size_t)(row0 + sr[i]) * 128 + sc[i] * 8;
        aRa[i] = *(const float4*)(src);
        aRb[i] = *(const float4*)(src + 4);
        size_t gb = (size_t)sr[i] * 256 + sc[i] * 16;
        wR[i][0] = *(const uint4*)((const char*)Wt0 + gb);
        wR[i][1] = *(const uint4*)((const char*)Wt1 + gb);
        wR[i][2] = *(const uint4*)((const char*)Wt2 + gb);
    }

#pragma unroll 1
    for (int kh = 0; kh < 4; kh++) {
        if (kh) __syncthreads();     // prev chunk's frag reads complete

        // ---- split prefetched A in regs + write LDS; copy W to LDS (R5 layout) ----
#pragma unroll
        for (int i = 0; i < 2; i++) {
            float a[8] = {aRa[i].x, aRa[i].y, aRa[i].z, aRa[i].w,
                          aRb[i].x, aRb[i].y, aRb[i].z, aRb[i].w};
            unsigned int h[8], m[8], lo[8];
#pragma unroll
            for (int j = 0; j < 8; j++) {
                h[j] = f2bf(a[j]);
                float r1 = a[j] - bf2f(h[j]);
                m[j] = f2bf(r1);
                float r2 = r1 - bf2f(m[j]);
                lo[j] = f2bf(r2);
            }
            *(uint4*)(sA0 + soff[i]) = make_uint4(h[0] | (h[1] << 16), h[2] | (h[3] << 16),
                                                  h[4] | (h[5] << 16), h[6] | (h[7] << 16));
            *(uint4*)(sA1 + soff[i]) = make_uint4(m[0] | (m[1] << 16), m[2] | (m[3] << 16),
                                                  m[4] | (m[5] << 16), m[6] | (m[7] << 16));
            *(uint4*)(sA2 + soff[i]) = make_uint4(lo[0] | (lo[1] << 16), lo[2] | (lo[3] << 16),
                                                  lo[4] | (lo[5] << 16), lo[6] | (lo[7] << 16));
            *(uint4*)(sW0 + soff[i]) = wR[i][0];
            *(uint4*)(sW1 + soff[i]) = wR[i][1];
            *(uint4*)(sW2 + soff[i]) = wR[i][2];
        }
        __syncthreads();

        // ---- issue next-chunk raw loads: in flight under the MFMA burst ----
        if (kh < 3) {
#pragma unroll
            for (int i = 0; i < 2; i++) {
                const float* src = hio + (size_t)(row0 + sr[i]) * 128 + (kh + 1) * 32 + sc[i] * 8;
                aRa[i] = *(const float4*)(src);
                aRb[i] = *(const float4*)(src + 4);
                size_t gb = (size_t)sr[i] * 256 + (kh + 1) * 64 + sc[i] * 16;
                wR[i][0] = *(const uint4*)((const char*)Wt0 + gb);
                wR[i][1] = *(const uint4*)((const char*)Wt1 + gb);
                wR[i][2] = *(const uint4*)((const char*)Wt2 + gb);
            }
        }

        // ---- fragments + MFMA (verbatim R5 order) ----
        s8v ah[2], am[2], al[2];
#pragma unroll
        for (int mt = 0; mt < 2; mt++) {
            int r = w * 32 + mt * 16 + l15;
            int off = r * 64 + ((l4 ^ ((r >> 1) & 3)) * 16);
            ah[mt] = *(const s8v*)(sA0 + off);
            am[mt] = *(const s8v*)(sA1 + off);
            al[mt] = *(const s8v*)(sA2 + off);
        }
#pragma unroll
        for (int nt = 0; nt < 8; nt++) {
            int rn = nt * 16 + l15;
            int offb = rn * 64 + ((l4 ^ ((rn >> 1) & 3)) * 16);
            s8v b0 = *(const s8v*)(sW0 + offb);
            s8v b1 = *(const s8v*)(sW1 + offb);
            s8v b2 = *(const s8v*)(sW2 + offb);
#pragma unroll
            for (int mt = 0; mt < 2; mt++) {
                acc[mt][nt] = __builtin_amdgcn_mfma_f32_16x16x32_bf16(ah[mt], b0, acc[mt][nt], 0, 0, 0);
                acc[mt][nt] = __builtin_amdgcn_mfma_f32_16x16x32_bf16(ah[mt], b1, acc[mt][nt], 0, 0, 0);
                acc[mt][nt] = __builtin_amdgcn_mfma_f32_16x16x32_bf16(am[mt], b0, acc[mt][nt], 0, 0, 0);
                acc[mt][nt] = __builtin_amdgcn_mfma_f32_16x16x32_bf16(am[mt], b1, acc[mt][nt], 0, 0, 0);
                acc[mt][nt] = __builtin_amdgcn_mfma_f32_16x16x32_bf16(ah[mt], b2, acc[mt][nt], 0, 0, 0);
                acc[mt][nt] = __builtin_amdgcn_mfma_f32_16x16x32_bf16(al[mt], b0, acc[mt][nt], 0, 0, 0);
                acc[mt][nt] = __builtin_amdgcn_mfma_f32_16x16x32_bf16(am[mt], b2, acc[mt][nt], 0, 0, 0);
                acc[mt][nt] = __builtin_amdgcn_mfma_f32_16x16x32_bf16(al[mt], b1, acc[mt][nt], 0, 0, 0);
            }
        }
    }

    // ---- epilogue: bias + leaky + h write (in-place) + score (verbatim R5) ----
    float bv[8], pv[8];
#pragma unroll
    for (int nt = 0; nt < 8; nt++) {
        bv[nt] = bias[nt * 16 + l15];
        pv[nt] = pw[nt * 16 + l15];
    }
    float nrm = normPw[0];
    float sp[2][4];
#pragma unroll
    for (int mt = 0; mt < 2; mt++)
#pragma unroll
        for (int r = 0; r < 4; r++) sp[mt][r] = 0.f;

#pragma unroll
    for (int mt = 0; mt < 2; mt++) {
#pragma unroll
        for (int r = 0; r < 4; r++) {
            int row = row0 + w * 32 + mt * 16 + l4 * 4 + r;
#pragma unroll
            for (int nt = 0; nt < 8; nt++) {
                float v = acc[mt][nt][r] + bv[nt];
                v = (v >= 0.f) ? v : NEG_SLOPE * v;
                hio[(size_t)row * 128 + nt * 16 + l15] = v;
                sp[mt][r] += v * pv[nt];
            }
        }
    }
#pragma unroll
    for (int m = 1; m < 16; m <<= 1) {
#pragma unroll
        for (int mt = 0; mt < 2; mt++)
#pragma unroll
            for (int r = 0; r < 4; r++) sp[mt][r] += __shfl_xor(sp[mt][r], m, 64);
    }
    if (l15 == 0) {
#pragma unroll
        for (int mt = 0; mt < 2; mt++)
#pragma unroll
            for (int r = 0; r < 4; r++) {
                int row = row0 + w * 32 + mt * 16 + l4 * 4 + r;
                score[row] = tanhf(sp[mt][r] / nrm);
            }
    }
}

// ================= K7: per-chunk LDS bitonic sort (128 blocks x 2048 keys) =================
__global__ void __launch_bounds__(1024) k_sortchunks(const float* score,
                                                     unsigned long long* keys) {
    __shared__ unsigned long long a[CHUNK];     // 16 KB
    int base = blockIdx.x * CHUNK;              // chunk-aligned within a graph
    int t = threadIdx.x;
#pragma unroll
    for (int i = 0; i < CHUNK / 1024; i++) {
        int p = t + i * 1024;
        int node = base + p;
        a[p] = pack_key(score[node], node & (N_PER - 1));
    }
    __syncthreads();
    for (int k = 2; k <= CHUNK; k <<= 1) {
        for (int j = k >> 1; j > 0; j >>= 1) {
#pragma unroll
            for (int q = 0; q < CHUNK / 2048; q++) {
                int tt = t + q * 1024;
                int i = ((tt & ~(j - 1)) << 1) | (tt & (j - 1));
                int l = i | j;
                bool asc = ((i & k) == 0);
                unsigned long long x = a[i], y = a[l];
                if ((x > y) == asc) { a[i] = y; a[l] = x; }
            }
            __syncthreads();
        }
    }
#pragma unroll
    for (int i = 0; i < CHUNK / 1024; i++) {
        int p = t + i * 1024;
        keys[base + p] = a[p];
    }
}

// ================= K8: rank via binary search over sorted chunks, fused extract =================
__global__ void k_rank(const float* score, const unsigned long long* keys,
                       int* perm, int* mapping, float* out) {
    int n = blockIdx.x * 256 + threadIdx.x;
    if (n >= N_NODES) return;
    int g = n >> 14;
    unsigned long long key = pack_key(score[n], n & (N_PER - 1));
    const unsigned long long* gb = keys + ((size_t)g << 14);
    int r = 0;
#pragma unroll
    for (int c = 0; c < N_PER / CHUNK; c++) {
        const unsigned long long* ch = gb + c * CHUNK;
        int lo = 0, hi = CHUNK;
        while (lo < hi) {
            int mid = (lo + hi) >> 1;
            if (ch[mid] < key) lo = mid + 1; else hi = mid;
        }
        r += lo;
    }
    if (r < KKEEP) {
        int i = (g << 13) + r;
        perm[i] = n;
        mapping[n] = i;
        out[X_BATCH + i] = (float)g;
    }
}

// ================= K10: gate kept rows =================
__global__ void k_gate(const float* h, const float* score, const int* perm, float* out) {
    int g = blockIdx.x * 256 + threadIdx.x;
    int i = g >> 5, d = g & 31;
    int node = perm[i];
    float sc = score[node];
    float4 v = ((const float4*)h)[(size_t)node * 32 + d];
    v.x *= sc; v.y *= sc; v.z *= sc; v.w *= sc;
    ((float4*)(out + X_OUT))[(size_t)i * 32 + d] = v;
}

// ================= K11: relabel edges =================
__global__ void k_edges(const int* row, const int* col, const float* w,
                        const int* mapping, float* out) {
    int e = blockIdx.x * 256 + threadIdx.x;
    if (e >= N_EDGES) return;
    int mr = mapping[row[e]], mc = mapping[col[e]];
    bool valid = (mr >= 0) && (mc >= 0);
    out[X_EI + e]           = valid ? (float)mr : 0.f;
    out[X_EI + N_EDGES + e] = valid ? (float)mc : 0.f;
    out[X_EW + e]           = valid ? w[e] : 0.f;
}

extern "C" void kernel_launch(void* const* d_in, const int* in_sizes, int n_in,
                              void* d_out, int out_size, void* d_ws, size_t ws_size,
                              hipStream_t stream) {
    const float* x     = (const float*)d_in[0];
    const int*   ei    = (const int*)d_in[1];
    const float* ew    = (const float*)d_in[2];
    const float* Wc    = (const float*)d_in[4];
    const float* bias  = (const float*)d_in[5];
    const float* pw    = (const float*)d_in[6];
    float* out = (float*)d_out;

    const int* rowp = ei;
    const int* colp = ei + N_EDGES;

    char* wsb = (char*)d_ws;
    float* agg     = (float*)(wsb);                          // N*128*4 = 134217728
    float* dinv    = (float*)(wsb + 134217728);              // N*4 (deg, then dinv)
    int*   count   = (int*)  (wsb + 135266304);              // N*4 (counts, then cursor)
    int*   offs    = (int*)  (wsb + 136314880);              // (N+1)*4 padded
    int*   ssrc    = (int*)  (wsb + 137363712);              // E*4
    float* scoef   = (float*)(wsb + 139460864);              // E*4
    float* score   = (float*)(wsb + 141557760);              // N*4
    unsigned long long* keys = (unsigned long long*)(wsb + 142606336);  // N*8
    int*   perm    = (int*)  (wsb + 144703488);              // B*K*4
    int*   mapping = (int*)  (wsb + 145227776);              // N*4
    int*   blockSums = (int*)(wsb + 146276352);              // 128*4 padded
    float* normPw  = (float*)(wsb + 146277376);              // 4
    unsigned short* Wt0 = (unsigned short*)(wsb + 146278400);  // 128*128*2 = 32768
    unsigned short* Wt1 = (unsigned short*)(wsb + 146311168);  // 32768
    unsigned short* Wt2 = (unsigned short*)(wsb + 146343936);  // 32768

    k_init   <<<N_NODES / 256, 256, 0, stream>>>(dinv, count, mapping, pw, normPw);
    k_wprep  <<<64, 256, 0, stream>>>(Wc, Wt0, Wt1, Wt2);
    k_deg    <<<N_EDGES / 256, 256, 0, stream>>>(colp, ew, dinv, count);
    k_scan1  <<<128, 1024, 0, stream>>>(count, offs, blockSums);
    k_scan2  <<<1, 64, 0, stream>>>(blockSums, offs);
    k_fixup  <<<N_NODES / 256, 256, 0, stream>>>(offs, count, dinv, blockSums);
    k_scatter<<<N_EDGES / 256, 256, 0, stream>>>(rowp, colp, ew, dinv, offs, count, ssrc, scoef);
    k_aggregate<<<(N_NODES * 32) / 256, 256, 0, stream>>>(x, dinv, offs, ssrc, scoef, agg);
    k_gemm   <<<N_NODES / 128, 256, 0, stream>>>(agg, Wt0, Wt1, Wt2, bias, pw, normPw, score);
    k_sortchunks<<<N_NODES / CHUNK, 1024, 0, stream>>>(score, keys);
    k_rank   <<<N_NODES / 256, 256, 0, stream>>>(score, keys, perm, mapping, out);
    k_gate   <<<(NB * KKEEP * 32) / 256, 256, 0, stream>>>(agg, score, perm, out);
    k_edges  <<<N_EDGES / 256, 256, 0, stream>>>(rowp, colp, ew, mapping, out);
}